// Round 8
// baseline (301.096 us; speedup 1.0000x reference)
//
#include <hip/hip_runtime.h>
#include <cstdint>

#define M_ 8192
#define N_ 4096
#define K_ 4096

typedef unsigned short u16;
typedef __bf16 bf16x8 __attribute__((ext_vector_type(8)));
typedef float  f32x4  __attribute__((ext_vector_type(4)));
typedef u16    u16x8  __attribute__((ext_vector_type(8)));

__device__ __forceinline__ u16 f2bf(float f) {
  union { float f; uint32_t u; } v; v.f = f;
  uint32_t u = v.u;
  return (u16)((u + 0x7fffu + ((u >> 16) & 1u)) >> 16);  // RNE
}

__device__ __forceinline__ void async16(const u16* g, void* l) {
  __builtin_amdgcn_global_load_lds(
      (const __attribute__((address_space(1))) void*)g,
      (__attribute__((address_space(3))) void*)l, 16, 0, 0);
}

// ---------------- prologue: x (f32) -> bf16 ----------------
__global__ void cvt_x_kernel(const float* __restrict__ x, u16* __restrict__ xb) {
  const long total8 = (long)M_ * K_ / 8;
  long t = (long)blockIdx.x * blockDim.x + threadIdx.x;
  const long stride = (long)gridDim.x * blockDim.x;
  for (; t < total8; t += stride) {
    long e = t * 8;
    float4 a = *(const float4*)(x + e);
    float4 b = *(const float4*)(x + e + 4);
    u16x8 r;
    r[0] = f2bf(a.x); r[1] = f2bf(a.y); r[2] = f2bf(a.z); r[3] = f2bf(a.w);
    r[4] = f2bf(b.x); r[5] = f2bf(b.y); r[6] = f2bf(b.z); r[7] = f2bf(b.w);
    *(u16x8*)(xb + e) = r;
  }
}

// ---------------- prologue: W dequant -> bf16 ----------------
__global__ void build_w_kernel(const int* __restrict__ wi, const float* __restrict__ zp,
                               const float* __restrict__ dout, const float* __restrict__ din,
                               const int* __restrict__ eidx, u16* __restrict__ wb) {
  const int e = *eidx;
  const long total8 = (long)N_ * K_ / 8;
  long t = (long)blockIdx.x * blockDim.x + threadIdx.x;
  const long stride = (long)gridDim.x * blockDim.x;
  const float* dine = din + (long)e * K_;
  const float* doute = dout + (long)e * N_;
  for (; t < total8; t += stride) {
    long eo = t * 8;
    int o = (int)(eo >> 12);
    int c = (int)(eo & (K_ - 1));
    float z  = zp[o];
    float so = doute[o];
    int4 w0 = *(const int4*)(wi + eo);
    int4 w1 = *(const int4*)(wi + eo + 4);
    float4 d0 = *(const float4*)(dine + c);
    float4 d1 = *(const float4*)(dine + c + 4);
    u16x8 r;
    r[0] = f2bf(((float)w0.x - z) * so * d0.x);
    r[1] = f2bf(((float)w0.y - z) * so * d0.y);
    r[2] = f2bf(((float)w0.z - z) * so * d0.z);
    r[3] = f2bf(((float)w0.w - z) * so * d0.w);
    r[4] = f2bf(((float)w1.x - z) * so * d1.x);
    r[5] = f2bf(((float)w1.y - z) * so * d1.y);
    r[6] = f2bf(((float)w1.z - z) * so * d1.z);
    r[7] = f2bf(((float)w1.w - z) * so * d1.w);
    *(u16x8*)(wb + eo) = r;
  }
}

// ---- main GEMM: 256x256, BK=64, dbuf, ONE phase/tile, SGB-forced interleave ----
// LDS per 64KB buffer (regions 16KB): Alo/Ahi split A rows by local bit-6;
// Blo/Bhi split B cols by bit-5 (g&32), row = ((g>>6)<<5)|(g&31)  [round-6-proven].
// Tile body: stage 8 gloads for t+1 -> VMC(8) -> BAR -> sched_barrier(0) ->
// [6 pre-reads; 16 groups {1-2 ds_read (for group g+2); 4 MFMA} pinned by
// sched_group_barrier chain] -> BAR.
// Swizzle: 16B slot ^= (row&7) within 128B rows (both sides, rule #21).
#define VMC(n)   asm volatile("s_waitcnt vmcnt(" #n ")" ::: "memory")
#define BAR()    __builtin_amdgcn_s_barrier()
#define RD(p)    (*(const bf16x8*)(p))
#define SGB(m,n) __builtin_amdgcn_sched_group_barrier((m), (n), 0)

__global__ __launch_bounds__(512, 2) void gemm_kernel(const u16* __restrict__ A,
                                                      const u16* __restrict__ B,
                                                      const float* __restrict__ bias,
                                                      float* __restrict__ C) {
  extern __shared__ char ldsb[];
  const int tid  = threadIdx.x;
  const int lane = tid & 63;
  const int wave = tid >> 6;
  const int wm = wave >> 2;            // 0..1 -> 128-row half of A-tile
  const int wn = wave & 3;             // 0..3 -> 64-col quarter of B-tile
  const int fr = lane & 15, fq = lane >> 4;

  // XCD-aware swizzle (512 % 8 == 0 -> bijective)
  const int nwg = gridDim.x;
  const int wg  = blockIdx.x;
  const int swz = (wg & 7) * (nwg >> 3) + (wg >> 3);
  const int bm = swz >> 4;
  const int bn = swz & 15;
  const long brow = (long)bm * 256;
  const long bcol = (long)bn * 256;

  // ---- staging geometry (round-6-proven mappings) ----
  const int slot_g = (tid & 7) ^ ((tid >> 3) & 7);   // inverse-swizzled src slot
  const int tr = tid >> 3;                           // 0..63
  const int b0row = (tr & 31) + ((tr >> 5) << 6);
  const u16* pA0 = A + (brow + tr) * (long)K_ + slot_g * 8;
  const u16* pB0 = B + (bcol + b0row) * (long)K_ + slot_g * 8;

  auto STAGE_A = [&](int tile, int h) {
    char* dst = ldsb + (tile & 1) * 65536 + h * 16384 + tid * 16;
    const long ko = (long)tile * 64 + (long)h * 64 * K_;
    async16(pA0 + ko, dst);
    async16(pA0 + ko + 128 * (long)K_, dst + 8192);
  };
  auto STAGE_B = [&](int tile, int h) {
    char* dst = ldsb + (tile & 1) * 65536 + 32768 + h * 16384 + tid * 16;
    const long ko = (long)tile * 64 + (long)h * 32 * K_;
    async16(pB0 + ko, dst);
    async16(pB0 + ko + 128 * (long)K_, dst + 8192);
  };

  // ---- ds_read offsets (elements from buffer base) ----
  const int swk0 = ((fq ^ (fr & 7)) << 3);
  const int swk1 = (((4 + fq) ^ (fr & 7)) << 3);
  int rA[4], rB[2];
#pragma unroll
  for (int m = 0; m < 4; ++m) rA[m] = (m * 16 + fr + wm * 64) * 64;
#pragma unroll
  for (int n = 0; n < 2; ++n) rB[n] = (n * 16 + fr + wn * 32) * 64;

  f32x4 acc[8][4] = {};
  bf16x8 aK0[8], aK1[8], bK0[4], bK1[4];

#define RDA(mm, KK) RD((const u16*)cur + (((mm) < 4 ? 0 : 8192) + rA[(mm) & 3] + ((KK) ? swk1 : swk0)))
#define RDB(nn, KK) RD((const u16*)cur + (16384 + ((nn) < 2 ? 0 : 8192) + rB[(nn) & 1] + ((KK) ? swk1 : swk0)))
#define G4(mm, AV, BARR)                                                           \
  acc[mm][0] = __builtin_amdgcn_mfma_f32_16x16x32_bf16(AV, BARR[0], acc[mm][0], 0, 0, 0); \
  acc[mm][1] = __builtin_amdgcn_mfma_f32_16x16x32_bf16(AV, BARR[1], acc[mm][1], 0, 0, 0); \
  acc[mm][2] = __builtin_amdgcn_mfma_f32_16x16x32_bf16(AV, BARR[2], acc[mm][2], 0, 0, 0); \
  acc[mm][3] = __builtin_amdgcn_mfma_f32_16x16x32_bf16(AV, BARR[3], acc[mm][3], 0, 0, 0);
#define SG1 SGB(0x100, 1); SGB(0x8, 4);
#define SG2 SGB(0x100, 2); SGB(0x8, 4);
#define SG0 SGB(0x8, 4);

  const int nk = K_ / 64;              // 64 K-tiles

  // prologue: stage tile 0 (8 loads)
  STAGE_A(0, 0); STAGE_A(0, 1); STAGE_B(0, 0); STAGE_B(0, 1);

  for (int t = 0; t < nk; ++t) {
    const char* cur = ldsb + (t & 1) * 65536;
    if (t + 1 < nk) {
      STAGE_A(t + 1, 0); STAGE_A(t + 1, 1); STAGE_B(t + 1, 0); STAGE_B(t + 1, 1);
      VMC(8);                          // tile t's 8 loads landed (t+1's in flight)
    } else {
      VMC(0);
    }
    BAR();
    __builtin_amdgcn_sched_barrier(0);

    // pre-reads: B[0..3]k0, A[0..1]k0
    bK0[0] = RDB(0, 0); bK0[1] = RDB(1, 0); bK0[2] = RDB(2, 0); bK0[3] = RDB(3, 0);
    aK0[0] = RDA(0, 0); aK0[1] = RDA(1, 0);
    SGB(0x100, 6);
    // kk=0 rows, reads 2 groups ahead
    aK0[2] = RDA(2, 0);                     G4(0, aK0[0], bK0) SG1
    aK0[3] = RDA(3, 0);                     G4(1, aK0[1], bK0) SG1
    aK0[4] = RDA(4, 0);                     G4(2, aK0[2], bK0) SG1
    aK0[5] = RDA(5, 0);                     G4(3, aK0[3], bK0) SG1
    aK0[6] = RDA(6, 0); bK1[0] = RDB(0, 1); G4(4, aK0[4], bK0) SG2
    aK0[7] = RDA(7, 0); bK1[1] = RDB(1, 1); G4(5, aK0[5], bK0) SG2
    aK1[0] = RDA(0, 1); bK1[2] = RDB(2, 1); G4(6, aK0[6], bK0) SG2
    aK1[1] = RDA(1, 1); bK1[3] = RDB(3, 1); G4(7, aK0[7], bK0) SG2
    // kk=1 rows
    aK1[2] = RDA(2, 1);                     G4(0, aK1[0], bK1) SG1
    aK1[3] = RDA(3, 1);                     G4(1, aK1[1], bK1) SG1
    aK1[4] = RDA(4, 1);                     G4(2, aK1[2], bK1) SG1
    aK1[5] = RDA(5, 1);                     G4(3, aK1[3], bK1) SG1
    aK1[6] = RDA(6, 1);                     G4(4, aK1[4], bK1) SG1
    aK1[7] = RDA(7, 1);                     G4(5, aK1[5], bK1) SG1
                                            G4(6, aK1[6], bK1) SG0
                                            G4(7, aK1[7], bK1) SG0
    __builtin_amdgcn_sched_barrier(0);
    BAR();
  }

#undef RDA
#undef RDB
#undef G4
#undef SG1
#undef SG2
#undef SG0

  // epilogue: C/D layout col=lane&15, row=(lane>>4)*4+reg  [m89-verified]
  const int  ocol0 = (int)bcol + wn * 64;
  const long orow0 = brow + wm * 128;
  float bv[4];
#pragma unroll
  for (int n = 0; n < 4; ++n) bv[n] = bias[ocol0 + n * 16 + fr];
#pragma unroll
  for (int m = 0; m < 8; ++m) {
    long rb = orow0 + m * 16 + fq * 4;
#pragma unroll
    for (int n = 0; n < 4; ++n) {
      int col = ocol0 + n * 16 + fr;
#pragma unroll
      for (int j = 0; j < 4; ++j)
        C[(rb + j) * N_ + col] = acc[m][n][j] + bv[n];
    }
  }
}

// ---------------- fallback (only if ws too small) ----------------
__global__ void naive_kernel(const float* __restrict__ x, const int* __restrict__ wi,
                             const float* __restrict__ zp, const float* __restrict__ dout,
                             const float* __restrict__ din, const float* __restrict__ bias,
                             const int* __restrict__ eidx, float* __restrict__ y) {
  long t = (long)blockIdx.x * blockDim.x + threadIdx.x;
  if (t >= (long)M_ * N_) return;
  int  o = (int)(t & (N_ - 1));
  long r = t >> 12;
  int  e = *eidx;
  float z  = zp[o];
  float so = dout[(long)e * N_ + o];
  const float* xr = x + r * K_;
  const int*   wrow = wi + (long)o * K_;
  const float* dr = din + (long)e * K_;
  float s = 0.f;
  for (int k = 0; k < K_; ++k)
    s += xr[k] * (((float)wrow[k] - z) * dr[k]);
  y[t] = s * so + bias[o];
}

extern "C" void kernel_launch(void* const* d_in, const int* in_sizes, int n_in,
                              void* d_out, int out_size, void* d_ws, size_t ws_size,
                              hipStream_t stream) {
  const float* x    = (const float*)d_in[0];
  const int*   wi   = (const int*)d_in[1];
  const float* zp   = (const float*)d_in[2];
  const float* dout = (const float*)d_in[3];
  const float* din  = (const float*)d_in[4];
  const float* bias = (const float*)d_in[5];
  const int*   eidx = (const int*)d_in[6];
  float* y = (float*)d_out;

  const size_t need = (size_t)M_ * K_ * 2 + (size_t)N_ * K_ * 2;
  if (ws_size >= need) {
    u16* xb = (u16*)d_ws;
    u16* wb = xb + (size_t)M_ * K_;
    cvt_x_kernel<<<dim3(2048), dim3(256), 0, stream>>>(x, xb);
    build_w_kernel<<<dim3(2048), dim3(256), 0, stream>>>(wi, zp, dout, din, eidx, wb);
    (void)hipFuncSetAttribute((const void*)gemm_kernel,
                              hipFuncAttributeMaxDynamicSharedMemorySize, 131072);
    gemm_kernel<<<dim3((M_ / 256) * (N_ / 256)), dim3(512), 131072, stream>>>(xb, wb, bias, y);
  } else {
    long total = (long)M_ * N_;
    naive_kernel<<<dim3((unsigned)((total + 255) / 256)), dim3(256), 0, stream>>>(
        x, wi, zp, dout, din, bias, eidx, y);
  }
}